// Round 4
// baseline (215.451 us; speedup 1.0000x reference)
//
#include <hip/hip_runtime.h>
// R3 resubmit: rounds 1-3 failed with broker-side UnresponsiveContainer before any GPU work.

#define B_ 8
#define N_ 512
#define IND 768
#define MEMD 300
#define HIDD 64
#define NEGINF (-1e30f)

__device__ inline unsigned fkey(float f){
  unsigned u = __float_as_uint(f);
  return (u & 0x80000000u) ? ~u : (u | 0x80000000u);
}
__device__ inline float fdec(unsigned k){
  unsigned u = (k & 0x80000000u) ? (k & 0x7fffffffu) : ~k;
  return __uint_as_float(u);
}
__device__ inline float waveRedSum(float v){
  #pragma unroll
  for (int o = 32; o > 0; o >>= 1) v += __shfl_down(v, o, 64);
  return v;
}
__device__ inline float waveRedMax(float v){
  #pragma unroll
  for (int o = 32; o > 0; o >>= 1) v = fmaxf(v, __shfl_down(v, o, 64));
  return v;
}

// K1: h = feature @ W_w^T + W_b   [4096 x 300], K=768
__global__ __launch_bounds__(256) void k1_h(const float* __restrict__ A,
                                            const float* __restrict__ W,
                                            const float* __restrict__ Wb,
                                            float* __restrict__ H){
  __shared__ float As[64][17];
  __shared__ float Bs[64][17];
  const int m0 = blockIdx.y * 64;
  const int c0 = blockIdx.x * 64;
  const int t  = threadIdx.x;
  const int tr = t >> 4, tc = t & 15;
  const int lr = t >> 2, lk = (t & 3) * 4;
  float acc[4][4] = {};
  for (int kt = 0; kt < IND; kt += 16){
    float4 ga = *(const float4*)&A[(size_t)(m0 + lr) * IND + kt + lk];
    float4 gb = make_float4(0.f,0.f,0.f,0.f);
    int brow = c0 + lr;
    if (brow < MEMD) gb = *(const float4*)&W[(size_t)brow * IND + kt + lk];
    __syncthreads();
    As[lr][lk+0]=ga.x; As[lr][lk+1]=ga.y; As[lr][lk+2]=ga.z; As[lr][lk+3]=ga.w;
    Bs[lr][lk+0]=gb.x; Bs[lr][lk+1]=gb.y; Bs[lr][lk+2]=gb.z; Bs[lr][lk+3]=gb.w;
    __syncthreads();
    #pragma unroll
    for (int kk = 0; kk < 16; kk++){
      float a0 = As[tr*4+0][kk], a1 = As[tr*4+1][kk];
      float a2 = As[tr*4+2][kk], a3 = As[tr*4+3][kk];
      float b0 = Bs[tc*4+0][kk], b1 = Bs[tc*4+1][kk];
      float b2 = Bs[tc*4+2][kk], b3 = Bs[tc*4+3][kk];
      acc[0][0] += a0*b0; acc[0][1] += a0*b1; acc[0][2] += a0*b2; acc[0][3] += a0*b3;
      acc[1][0] += a1*b0; acc[1][1] += a1*b1; acc[1][2] += a1*b2; acc[1][3] += a1*b3;
      acc[2][0] += a2*b0; acc[2][1] += a2*b1; acc[2][2] += a2*b2; acc[2][3] += a2*b3;
      acc[3][0] += a3*b0; acc[3][1] += a3*b1; acc[3][2] += a3*b2; acc[3][3] += a3*b3;
    }
  }
  #pragma unroll
  for (int i = 0; i < 4; i++){
    int row = m0 + tr*4 + i;
    #pragma unroll
    for (int jj = 0; jj < 4; jj++){
      int col = c0 + tc*4 + jj;
      if (col < MEMD) H[(size_t)row * MEMD + col] = acc[i][jj] + Wb[col];
    }
  }
}

// K2: S = h @ Bmat^T, Bmat[c][k] = c<64 ? a1_w[c][k] : a1_w[c-64][300+k]; +a1_b on cols<64
__global__ __launch_bounds__(256) void k2_s(const float* __restrict__ Hm,
                                            const float* __restrict__ a1w,
                                            const float* __restrict__ a1b,
                                            float* __restrict__ S){
  __shared__ float As[64][17];
  __shared__ float Bs[64][17];
  const int m0 = blockIdx.y * 64;
  const int c0 = blockIdx.x * 64;
  const int t  = threadIdx.x;
  const int tr = t >> 4, tc = t & 15;
  const int lr = t >> 2, lk = (t & 3) * 4;
  float acc[4][4] = {};
  for (int kt = 0; kt < 304; kt += 16){
    int k = kt + lk;
    float4 ga = make_float4(0.f,0.f,0.f,0.f);
    float4 gb = make_float4(0.f,0.f,0.f,0.f);
    if (k < MEMD){
      ga = *(const float4*)&Hm[(size_t)(m0 + lr) * MEMD + k];
      int brow = c0 + lr;
      const float* src = (brow < 64) ? &a1w[(size_t)brow * 600 + k]
                                     : &a1w[(size_t)(brow - 64) * 600 + 300 + k];
      gb = *(const float4*)src;
    }
    __syncthreads();
    As[lr][lk+0]=ga.x; As[lr][lk+1]=ga.y; As[lr][lk+2]=ga.z; As[lr][lk+3]=ga.w;
    Bs[lr][lk+0]=gb.x; Bs[lr][lk+1]=gb.y; Bs[lr][lk+2]=gb.z; Bs[lr][lk+3]=gb.w;
    __syncthreads();
    #pragma unroll
    for (int kk = 0; kk < 16; kk++){
      float a0 = As[tr*4+0][kk], a1 = As[tr*4+1][kk];
      float a2 = As[tr*4+2][kk], a3 = As[tr*4+3][kk];
      float b0 = Bs[tc*4+0][kk], b1 = Bs[tc*4+1][kk];
      float b2 = Bs[tc*4+2][kk], b3 = Bs[tc*4+3][kk];
      acc[0][0] += a0*b0; acc[0][1] += a0*b1; acc[0][2] += a0*b2; acc[0][3] += a0*b3;
      acc[1][0] += a1*b0; acc[1][1] += a1*b1; acc[1][2] += a1*b2; acc[1][3] += a1*b3;
      acc[2][0] += a2*b0; acc[2][1] += a2*b1; acc[2][2] += a2*b2; acc[2][3] += a2*b3;
      acc[3][0] += a3*b0; acc[3][1] += a3*b1; acc[3][2] += a3*b2; acc[3][3] += a3*b3;
    }
  }
  #pragma unroll
  for (int i = 0; i < 4; i++){
    int row = m0 + tr*4 + i;
    #pragma unroll
    for (int jj = 0; jj < 4; jj++){
      int col = c0 + tc*4 + jj;
      float bias = (col < 64) ? a1b[col] : 0.f;
      S[(size_t)row * 128 + col] = acc[i][jj] + bias;
    }
  }
}

// K3: l = mask(leaky(sum_k relu(si+sj)*a2w + a2b)); per-batch max via keyed atomicMax
__global__ __launch_bounds__(256) void k3_logits(const float* __restrict__ S,
                                                 const float* __restrict__ adj,
                                                 const float* __restrict__ a2w,
                                                 const float* __restrict__ a2b,
                                                 float* __restrict__ L,
                                                 unsigned* __restrict__ mk){
  __shared__ float si_s[32][64];
  __shared__ float sj_s[64][64];
  __shared__ float w_s[64];
  __shared__ float redm[4];
  const int b  = blockIdx.z;
  const int i0 = blockIdx.y * 32;
  const int j0 = blockIdx.x * 64;
  const int t  = threadIdx.x;
  if (t < 16) *(float4*)&w_s[t*4] = *(const float4*)&a2w[t*4];
  #pragma unroll
  for (int q = 0; q < 2; q++){
    int c = t + q*256; int r = c >> 4, c4 = c & 15;
    *(float4*)&si_s[r][c4*4] = *(const float4*)&S[(size_t)(b*N_ + i0 + r)*128 + c4*4];
  }
  #pragma unroll
  for (int q = 0; q < 4; q++){
    int c = t + q*256; int r = c >> 4, c4 = c & 15;
    int c4s = c4 ^ (r & 7);                 // XOR swizzle vs 256B-stride bank alias
    *(float4*)&sj_s[r][c4s*4] = *(const float4*)&S[(size_t)(b*N_ + j0 + r)*128 + 64 + c4*4];
  }
  __syncthreads();
  const int j = t & 63, iq = t >> 6;
  const float a2bv = a2b[0];
  float4 acc[8];
  #pragma unroll
  for (int ii = 0; ii < 8; ii++) acc[ii] = make_float4(0.f,0.f,0.f,0.f);
  #pragma unroll
  for (int k4 = 0; k4 < 16; k4++){
    float4 sj4 = *(float4*)&sj_s[j][(k4 ^ (j & 7))*4];
    float4 w4  = *(float4*)&w_s[k4*4];
    #pragma unroll
    for (int ii = 0; ii < 8; ii++){
      int i = ii*4 + iq;                    // iq uniform per wave -> broadcast
      float4 si4 = *(float4*)&si_s[i][k4*4];
      acc[ii].x += fmaxf(si4.x + sj4.x, 0.f) * w4.x;
      acc[ii].y += fmaxf(si4.y + sj4.y, 0.f) * w4.y;
      acc[ii].z += fmaxf(si4.z + sj4.z, 0.f) * w4.z;
      acc[ii].w += fmaxf(si4.w + sj4.w, 0.f) * w4.w;
    }
  }
  float locmax = -3e38f;
  #pragma unroll
  for (int ii = 0; ii < 8; ii++){
    int i = ii*4 + iq;
    float e = ((acc[ii].x + acc[ii].y) + (acc[ii].z + acc[ii].w)) + a2bv;
    e = (e >= 0.f) ? e : 0.01f * e;
    size_t idx = (size_t)(b*N_ + i0 + i)*N_ + j0 + j;
    float l = (adj[idx] != 0.f) ? e : NEGINF;
    L[idx] = l;
    locmax = fmaxf(locmax, l);
  }
  float m = waveRedMax(locmax);
  if ((t & 63) == 0) redm[t >> 6] = m;
  __syncthreads();
  if (t == 0){
    float mm = fmaxf(fmaxf(redm[0], redm[1]), fmaxf(redm[2], redm[3]));
    atomicMax(mk + b, fkey(mm));
  }
}

// K5: partial sums of exp(l - max_b)
__global__ __launch_bounds__(256) void k5_sum(const float* __restrict__ L,
                                              const unsigned* __restrict__ mk,
                                              float* __restrict__ partial){
  const int b = blockIdx.y, blk = blockIdx.x, t = threadIdx.x;
  const float mx = fdec(mk[b]);
  const float4* p = (const float4*)&L[(size_t)b*262144 + (size_t)blk*2048 + t*8];
  float4 v0 = p[0], v1 = p[1];
  float s = __expf(v0.x-mx)+__expf(v0.y-mx)+__expf(v0.z-mx)+__expf(v0.w-mx)
          + __expf(v1.x-mx)+__expf(v1.y-mx)+__expf(v1.z-mx)+__expf(v1.w-mx);
  s = waveRedSum(s);
  __shared__ float r4[4];
  if ((t & 63) == 0) r4[t >> 6] = s;
  __syncthreads();
  if (t == 0) partial[b*128 + blk] = (r4[0]+r4[1]) + (r4[2]+r4[3]);
}

// K6: deterministic reduce of partials -> sums[b]
__global__ __launch_bounds__(128) void k6_red(const float* __restrict__ partial,
                                              float* __restrict__ sums){
  const int b = blockIdx.x, t = threadIdx.x;
  float v = partial[b*128 + t];
  v = waveRedSum(v);
  __shared__ float r2[2];
  if ((t & 63) == 0) r2[t >> 6] = v;
  __syncthreads();
  if (t == 0) sums[b] = r2[0] + r2[1];
}

// K7: out = (exp(l-max) @ h) * (1/sum_b); per-batch GEMM [512x300], K=512
__global__ __launch_bounds__(256) void k7_out(const float* __restrict__ L,
                                              const float* __restrict__ Hm,
                                              const unsigned* __restrict__ mk,
                                              const float* __restrict__ sums,
                                              float* __restrict__ out){
  __shared__ float As[64][17];
  __shared__ float Bs[16][64];
  const int b  = blockIdx.z;
  const int m0 = blockIdx.y * 64;
  const int c0 = blockIdx.x * 64;
  const int t  = threadIdx.x;
  const int tr = t >> 4, tc = t & 15;
  const int lr = t >> 2, lk = (t & 3) * 4;
  const int br = t >> 4, bc = (t & 15) * 4;
  const float mx = fdec(mk[b]);
  float acc[4][4] = {};
  const size_t Lb = (size_t)b * 262144;
  for (int kt = 0; kt < 512; kt += 16){
    float4 ga = *(const float4*)&L[Lb + (size_t)(m0 + lr)*512 + kt + lk];
    float4 gb = make_float4(0.f,0.f,0.f,0.f);
    int gcol = c0 + bc;
    if (gcol < MEMD) gb = *(const float4*)&Hm[(size_t)(b*N_ + kt + br)*MEMD + gcol];
    __syncthreads();
    As[lr][lk+0] = __expf(ga.x - mx);
    As[lr][lk+1] = __expf(ga.y - mx);
    As[lr][lk+2] = __expf(ga.z - mx);
    As[lr][lk+3] = __expf(ga.w - mx);
    *(float4*)&Bs[br][bc] = gb;
    __syncthreads();
    #pragma unroll
    for (int kk = 0; kk < 16; kk++){
      float a0 = As[tr*4+0][kk], a1 = As[tr*4+1][kk];
      float a2 = As[tr*4+2][kk], a3 = As[tr*4+3][kk];
      float4 b4 = *(float4*)&Bs[kk][tc*4];
      acc[0][0] += a0*b4.x; acc[0][1] += a0*b4.y; acc[0][2] += a0*b4.z; acc[0][3] += a0*b4.w;
      acc[1][0] += a1*b4.x; acc[1][1] += a1*b4.y; acc[1][2] += a1*b4.z; acc[1][3] += a1*b4.w;
      acc[2][0] += a2*b4.x; acc[2][1] += a2*b4.y; acc[2][2] += a2*b4.z; acc[2][3] += a2*b4.w;
      acc[3][0] += a3*b4.x; acc[3][1] += a3*b4.y; acc[3][2] += a3*b4.z; acc[3][3] += a3*b4.w;
    }
  }
  const float invs = 1.0f / sums[b];
  #pragma unroll
  for (int i = 0; i < 4; i++){
    int row = m0 + tr*4 + i;
    #pragma unroll
    for (int jj = 0; jj < 4; jj++){
      int col = c0 + tc*4 + jj;
      if (col < MEMD)
        out[(size_t)(b*N_ + row)*MEMD + col] = acc[i][jj] * invs;
    }
  }
}

extern "C" void kernel_launch(void* const* d_in, const int* in_sizes, int n_in,
                              void* d_out, int out_size, void* d_ws, size_t ws_size,
                              hipStream_t stream){
  const float* adj  = (const float*)d_in[0];
  const float* feat = (const float*)d_in[1];
  const float* Ww   = (const float*)d_in[2];
  const float* Wb   = (const float*)d_in[3];
  const float* a1w  = (const float*)d_in[4];
  const float* a1b  = (const float*)d_in[5];
  const float* a2w  = (const float*)d_in[6];
  const float* a2b  = (const float*)d_in[7];
  float* out = (float*)d_out;
  char* ws = (char*)d_ws;

  float*    H       = (float*)(ws + 0);           // 4,915,200 B
  float*    S       = (float*)(ws + 4915200);     // 2,097,152 B
  float*    L       = (float*)(ws + 7012352);     // 8,388,608 B
  float*    partial = (float*)(ws + 15400960);    // 4,096 B
  float*    sums    = (float*)(ws + 15405056);    // 32 B
  unsigned* mk      = (unsigned*)(ws + 15405312); // 32 B

  hipMemsetAsync(mk, 0, 8 * sizeof(unsigned), stream);

  dim3 blk(256);
  dim3 g1(5, 64);    k1_h     <<<g1, blk, 0, stream>>>(feat, Ww, Wb, H);
  dim3 g2(2, 64);    k2_s     <<<g2, blk, 0, stream>>>(H, a1w, a1b, S);
  dim3 g3(8, 16, 8); k3_logits<<<g3, blk, 0, stream>>>(S, adj, a2w, a2b, L, mk);
  dim3 g5(128, 8);   k5_sum   <<<g5, blk, 0, stream>>>(L, mk, partial);
  k6_red<<<dim3(8), dim3(128), 0, stream>>>(partial, sums);
  dim3 g7(5, 8, 8);  k7_out   <<<g7, blk, 0, stream>>>(L, H, mk, sums, out);
}

// Round 5
// 165.681 us; speedup vs baseline: 1.3004x; 1.3004x over previous
//
#include <hip/hip_runtime.h>
// R4: microkernel rewrite. K1/K2/K7 -> 32x64 tiles, 2x4 acc/thread, transposed-LDS
// b64/b128 reads, KT=32. Grids: K1 640, K2 256, K7 640 blocks. K5 exps L in-place.

#define NEGINF (-1e30f)

__device__ inline unsigned fkey(float f){
  unsigned u = __float_as_uint(f);
  return (u & 0x80000000u) ? ~u : (u | 0x80000000u);
}
__device__ inline float fdec(unsigned k){
  unsigned u = (k & 0x80000000u) ? (k & 0x7fffffffu) : ~k;
  return __uint_as_float(u);
}
__device__ inline float waveRedSum(float v){
  #pragma unroll
  for (int o = 32; o > 0; o >>= 1) v += __shfl_down(v, o, 64);
  return v;
}
__device__ inline float waveRedMax(float v){
  #pragma unroll
  for (int o = 32; o > 0; o >>= 1) v = fmaxf(v, __shfl_down(v, o, 64));
  return v;
}
__device__ inline float4 f4z(){ return make_float4(0.f,0.f,0.f,0.f); }

// ---------------- K1: h = feature @ W_w^T + W_b  [4096 x 300], K=768 ----------------
// tile 32(M) x 64(N), 256 thr, 2x4 acc. grid (5, 128) = 640 blocks.
__global__ __launch_bounds__(256) void k1_h(const float* __restrict__ A,
                                            const float* __restrict__ W,
                                            const float* __restrict__ Wb,
                                            float* __restrict__ H){
  __shared__ float At[32][36];   // [k][m]
  __shared__ float Bt[32][68];   // [k][n]
  const int c0 = blockIdx.x * 64;
  const int m0 = blockIdx.y * 32;
  const int t  = threadIdx.x;
  const int tr2 = (t >> 4) * 2;        // acc row base (0..30)
  const int tc4 = (t & 15) * 4;        // acc col base (0..60)
  const int ar  = t >> 3;              // staging row   (0..31)
  const int ac  = (t & 7) * 4;         // staging k-col (0..28)
  float4 acc0 = f4z(), acc1 = f4z();
  for (int kt = 0; kt < 768; kt += 32){
    const float4 ga = *(const float4*)&A[(size_t)(m0 + ar) * 768 + kt + ac];
    const int br0 = c0 + ar, br1 = c0 + 32 + ar;
    float4 gb0 = f4z(), gb1 = f4z();
    if (br0 < 300) gb0 = *(const float4*)&W[(size_t)br0 * 768 + kt + ac];
    if (br1 < 300) gb1 = *(const float4*)&W[(size_t)br1 * 768 + kt + ac];
    __syncthreads();
    At[ac+0][ar] = ga.x;  At[ac+1][ar] = ga.y;  At[ac+2][ar] = ga.z;  At[ac+3][ar] = ga.w;
    Bt[ac+0][ar] = gb0.x; Bt[ac+1][ar] = gb0.y; Bt[ac+2][ar] = gb0.z; Bt[ac+3][ar] = gb0.w;
    Bt[ac+0][32+ar] = gb1.x; Bt[ac+1][32+ar] = gb1.y; Bt[ac+2][32+ar] = gb1.z; Bt[ac+3][32+ar] = gb1.w;
    __syncthreads();
    #pragma unroll
    for (int kk = 0; kk < 32; kk++){
      const float2 a2 = *(const float2*)&At[kk][tr2];
      const float4 b4 = *(const float4*)&Bt[kk][tc4];
      acc0.x += a2.x*b4.x; acc0.y += a2.x*b4.y; acc0.z += a2.x*b4.z; acc0.w += a2.x*b4.w;
      acc1.x += a2.y*b4.x; acc1.y += a2.y*b4.y; acc1.z += a2.y*b4.z; acc1.w += a2.y*b4.w;
    }
  }
  const int col = c0 + tc4;
  if (col < 300){
    const float4 bi = *(const float4*)&Wb[col];
    float4 o0 = make_float4(acc0.x+bi.x, acc0.y+bi.y, acc0.z+bi.z, acc0.w+bi.w);
    float4 o1 = make_float4(acc1.x+bi.x, acc1.y+bi.y, acc1.z+bi.z, acc1.w+bi.w);
    *(float4*)&H[(size_t)(m0 + tr2    ) * 300 + col] = o0;
    *(float4*)&H[(size_t)(m0 + tr2 + 1) * 300 + col] = o1;
  }
}

// ---------------- K2: S = h @ Bmat^T (+a1_b on cols<64)  [4096 x 128], K=300 --------
// tile 32x64, grid (2, 128) = 256 blocks. Bmat[c][k] = c<64 ? a1w[c][k] : a1w[c-64][300+k]
__global__ __launch_bounds__(256) void k2_s(const float* __restrict__ Hm,
                                            const float* __restrict__ a1w,
                                            const float* __restrict__ a1b,
                                            float* __restrict__ S){
  __shared__ float At[32][36];
  __shared__ float Bt[32][68];
  const int c0 = blockIdx.x * 64;
  const int m0 = blockIdx.y * 32;
  const int t  = threadIdx.x;
  const int tr2 = (t >> 4) * 2;
  const int tc4 = (t & 15) * 4;
  const int ar  = t >> 3;
  const int ac  = (t & 7) * 4;
  float4 acc0 = f4z(), acc1 = f4z();
  for (int kt = 0; kt < 320; kt += 32){
    const int k = kt + ac;
    float4 ga = f4z(), gb0 = f4z(), gb1 = f4z();
    if (k < 300){
      ga = *(const float4*)&Hm[(size_t)(m0 + ar) * 300 + k];
      const int br0 = c0 + ar, br1 = c0 + 32 + ar;
      gb0 = (br0 < 64) ? *(const float4*)&a1w[(size_t)br0 * 600 + k]
                       : *(const float4*)&a1w[(size_t)(br0 - 64) * 600 + 300 + k];
      gb1 = (br1 < 64) ? *(const float4*)&a1w[(size_t)br1 * 600 + k]
                       : *(const float4*)&a1w[(size_t)(br1 - 64) * 600 + 300 + k];
    }
    __syncthreads();
    At[ac+0][ar] = ga.x;  At[ac+1][ar] = ga.y;  At[ac+2][ar] = ga.z;  At[ac+3][ar] = ga.w;
    Bt[ac+0][ar] = gb0.x; Bt[ac+1][ar] = gb0.y; Bt[ac+2][ar] = gb0.z; Bt[ac+3][ar] = gb0.w;
    Bt[ac+0][32+ar] = gb1.x; Bt[ac+1][32+ar] = gb1.y; Bt[ac+2][32+ar] = gb1.z; Bt[ac+3][32+ar] = gb1.w;
    __syncthreads();
    #pragma unroll
    for (int kk = 0; kk < 32; kk++){
      const float2 a2 = *(const float2*)&At[kk][tr2];
      const float4 b4 = *(const float4*)&Bt[kk][tc4];
      acc0.x += a2.x*b4.x; acc0.y += a2.x*b4.y; acc0.z += a2.x*b4.z; acc0.w += a2.x*b4.w;
      acc1.x += a2.y*b4.x; acc1.y += a2.y*b4.y; acc1.z += a2.y*b4.z; acc1.w += a2.y*b4.w;
    }
  }
  const int col = c0 + tc4;
  float4 bi = f4z();
  if (col < 64) bi = *(const float4*)&a1b[col];
  float4 o0 = make_float4(acc0.x+bi.x, acc0.y+bi.y, acc0.z+bi.z, acc0.w+bi.w);
  float4 o1 = make_float4(acc1.x+bi.x, acc1.y+bi.y, acc1.z+bi.z, acc1.w+bi.w);
  *(float4*)&S[(size_t)(m0 + tr2    ) * 128 + col] = o0;
  *(float4*)&S[(size_t)(m0 + tr2 + 1) * 128 + col] = o1;
}

// ---------------- K3: fused per-edge MLP logits + mask + per-batch max --------------
__global__ __launch_bounds__(256) void k3_logits(const float* __restrict__ S,
                                                 const float* __restrict__ adj,
                                                 const float* __restrict__ a2w,
                                                 const float* __restrict__ a2b,
                                                 float* __restrict__ L,
                                                 unsigned* __restrict__ mk){
  __shared__ float si_s[32][64];
  __shared__ float sj_s[64][64];
  __shared__ float w_s[64];
  __shared__ float redm[4];
  const int b  = blockIdx.z;
  const int i0 = blockIdx.y * 32;
  const int j0 = blockIdx.x * 64;
  const int t  = threadIdx.x;
  if (t < 16) *(float4*)&w_s[t*4] = *(const float4*)&a2w[t*4];
  #pragma unroll
  for (int q = 0; q < 2; q++){
    int c = t + q*256; int r = c >> 4, c4 = c & 15;
    *(float4*)&si_s[r][c4*4] = *(const float4*)&S[(size_t)(b*512 + i0 + r)*128 + c4*4];
  }
  #pragma unroll
  for (int q = 0; q < 4; q++){
    int c = t + q*256; int r = c >> 4, c4 = c & 15;
    int c4s = c4 ^ (r & 7);                 // XOR swizzle vs 256B-stride bank alias
    *(float4*)&sj_s[r][c4s*4] = *(const float4*)&S[(size_t)(b*512 + j0 + r)*128 + 64 + c4*4];
  }
  __syncthreads();
  const int j = t & 63, iq = t >> 6;
  const float a2bv = a2b[0];
  float4 acc[8];
  #pragma unroll
  for (int ii = 0; ii < 8; ii++) acc[ii] = f4z();
  #pragma unroll
  for (int k4 = 0; k4 < 16; k4++){
    float4 sj4 = *(float4*)&sj_s[j][(k4 ^ (j & 7))*4];
    float4 w4  = *(float4*)&w_s[k4*4];
    #pragma unroll
    for (int ii = 0; ii < 8; ii++){
      int i = ii*4 + iq;                    // iq uniform per wave -> broadcast
      float4 si4 = *(float4*)&si_s[i][k4*4];
      acc[ii].x += fmaxf(si4.x + sj4.x, 0.f) * w4.x;
      acc[ii].y += fmaxf(si4.y + sj4.y, 0.f) * w4.y;
      acc[ii].z += fmaxf(si4.z + sj4.z, 0.f) * w4.z;
      acc[ii].w += fmaxf(si4.w + sj4.w, 0.f) * w4.w;
    }
  }
  float locmax = -3e38f;
  #pragma unroll
  for (int ii = 0; ii < 8; ii++){
    int i = ii*4 + iq;
    float e = ((acc[ii].x + acc[ii].y) + (acc[ii].z + acc[ii].w)) + a2bv;
    e = (e >= 0.f) ? e : 0.01f * e;
    size_t idx = (size_t)(b*512 + i0 + i)*512 + j0 + j;
    float l = (adj[idx] != 0.f) ? e : NEGINF;
    L[idx] = l;
    locmax = fmaxf(locmax, l);
  }
  float m = waveRedMax(locmax);
  if ((t & 63) == 0) redm[t >> 6] = m;
  __syncthreads();
  if (t == 0){
    float mm = fmaxf(fmaxf(redm[0], redm[1]), fmaxf(redm[2], redm[3]));
    atomicMax(mk + b, fkey(mm));
  }
}

// ---------------- K5: L <- exp(L - max_b) in-place; partial sums --------------------
__global__ __launch_bounds__(256) void k5_sum(float* __restrict__ L,
                                              const unsigned* __restrict__ mk,
                                              float* __restrict__ partial){
  const int b = blockIdx.y, blk = blockIdx.x, t = threadIdx.x;
  const float mx = fdec(mk[b]);
  float4* p = (float4*)&L[(size_t)b*262144 + (size_t)blk*2048 + t*8];
  float4 v0 = p[0], v1 = p[1];
  float4 e0 = make_float4(__expf(v0.x-mx), __expf(v0.y-mx), __expf(v0.z-mx), __expf(v0.w-mx));
  float4 e1 = make_float4(__expf(v1.x-mx), __expf(v1.y-mx), __expf(v1.z-mx), __expf(v1.w-mx));
  p[0] = e0; p[1] = e1;
  float s = (e0.x+e0.y)+(e0.z+e0.w) + (e1.x+e1.y)+(e1.z+e1.w);
  s = waveRedSum(s);
  __shared__ float r4[4];
  if ((t & 63) == 0) r4[t >> 6] = s;
  __syncthreads();
  if (t == 0) partial[b*128 + blk] = (r4[0]+r4[1]) + (r4[2]+r4[3]);
}

// ---------------- K6: deterministic reduce of partials -> sums[b] -------------------
__global__ __launch_bounds__(128) void k6_red(const float* __restrict__ partial,
                                              float* __restrict__ sums){
  const int b = blockIdx.x, t = threadIdx.x;
  float v = partial[b*128 + t];
  v = waveRedSum(v);
  __shared__ float r2[2];
  if ((t & 63) == 0) r2[t >> 6] = v;
  __syncthreads();
  if (t == 0) sums[b] = r2[0] + r2[1];
}

// ---------------- K7: out = (E @ h) / sum_b; per-batch [512x300], K=512 -------------
// tile 32x64, grid (5, 16, 8) = 640 blocks. E = exp'd L. B-staging is direct (no transpose).
__global__ __launch_bounds__(256) void k7_out(const float* __restrict__ E,
                                              const float* __restrict__ Hm,
                                              const float* __restrict__ sums,
                                              float* __restrict__ out){
  __shared__ float At[32][36];
  __shared__ float Bt[32][68];
  const int c0 = blockIdx.x * 64;
  const int m0 = blockIdx.y * 32;
  const int b  = blockIdx.z;
  const int t  = threadIdx.x;
  const int tr2 = (t >> 4) * 2;
  const int tc4 = (t & 15) * 4;
  const int ar  = t >> 3;
  const int ac  = (t & 7) * 4;
  const int kr  = t >> 4;              // B staging k-row (0..15)
  const int cg  = (t & 15) * 4;        // B staging col   (0..60)
  const int colB = c0 + cg;
  float4 acc0 = f4z(), acc1 = f4z();
  const size_t Eb = (size_t)b * 262144;
  const size_t Hb = (size_t)b * 512;
  for (int kt = 0; kt < 512; kt += 32){
    const float4 ga = *(const float4*)&E[Eb + (size_t)(m0 + ar)*512 + kt + ac];
    float4 gb0 = f4z(), gb1 = f4z();
    if (colB < 300){
      gb0 = *(const float4*)&Hm[(Hb + kt + kr     )*300 + colB];
      gb1 = *(const float4*)&Hm[(Hb + kt + 16 + kr)*300 + colB];
    }
    __syncthreads();
    At[ac+0][ar] = ga.x; At[ac+1][ar] = ga.y; At[ac+2][ar] = ga.z; At[ac+3][ar] = ga.w;
    *(float4*)&Bt[kr     ][cg] = gb0;
    *(float4*)&Bt[16 + kr][cg] = gb1;
    __syncthreads();
    #pragma unroll
    for (int kk = 0; kk < 32; kk++){
      const float2 a2 = *(const float2*)&At[kk][tr2];
      const float4 b4 = *(const float4*)&Bt[kk][tc4];
      acc0.x += a2.x*b4.x; acc0.y += a2.x*b4.y; acc0.z += a2.x*b4.z; acc0.w += a2.x*b4.w;
      acc1.x += a2.y*b4.x; acc1.y += a2.y*b4.y; acc1.z += a2.y*b4.z; acc1.w += a2.y*b4.w;
    }
  }
  const float invs = 1.0f / sums[b];
  const int col = c0 + tc4;
  if (col < 300){
    float4 o0 = make_float4(acc0.x*invs, acc0.y*invs, acc0.z*invs, acc0.w*invs);
    float4 o1 = make_float4(acc1.x*invs, acc1.y*invs, acc1.z*invs, acc1.w*invs);
    *(float4*)&out[(Hb + m0 + tr2    )*300 + col] = o0;
    *(float4*)&out[(Hb + m0 + tr2 + 1)*300 + col] = o1;
  }
}

extern "C" void kernel_launch(void* const* d_in, const int* in_sizes, int n_in,
                              void* d_out, int out_size, void* d_ws, size_t ws_size,
                              hipStream_t stream){
  const float* adj  = (const float*)d_in[0];
  const float* feat = (const float*)d_in[1];
  const float* Ww   = (const float*)d_in[2];
  const float* Wb   = (const float*)d_in[3];
  const float* a1w  = (const float*)d_in[4];
  const float* a1b  = (const float*)d_in[5];
  const float* a2w  = (const float*)d_in[6];
  const float* a2b  = (const float*)d_in[7];
  float* out = (float*)d_out;
  char* ws = (char*)d_ws;

  float*    H       = (float*)(ws + 0);           // 4,915,200 B
  float*    S       = (float*)(ws + 4915200);     // 2,097,152 B
  float*    L       = (float*)(ws + 7012352);     // 8,388,608 B
  float*    partial = (float*)(ws + 15400960);    // 4,096 B
  float*    sums    = (float*)(ws + 15405056);    // 32 B
  unsigned* mk      = (unsigned*)(ws + 15405312); // 32 B

  hipMemsetAsync(mk, 0, 8 * sizeof(unsigned), stream);

  dim3 blk(256);
  k1_h     <<<dim3(5, 128),   blk, 0, stream>>>(feat, Ww, Wb, H);
  k2_s     <<<dim3(2, 128),   blk, 0, stream>>>(H, a1w, a1b, S);
  k3_logits<<<dim3(8, 16, 8), blk, 0, stream>>>(S, adj, a2w, a2b, L, mk);
  k5_sum   <<<dim3(128, 8),   blk, 0, stream>>>(L, mk, partial);
  k6_red   <<<dim3(8), dim3(128), 0, stream>>>(partial, sums);
  k7_out   <<<dim3(5, 16, 8), blk, 0, stream>>>(L, H, sums, out);
}

// Round 7
// 147.134 us; speedup vs baseline: 1.4643x; 1.1261x over previous
//
#include <hip/hip_runtime.h>
// R6 resubmit (R7): pod died before compile on previous round; source unchanged.
// Stall fix: all GEMMs use register-prefetch + single-barrier double-buffered LDS,
// 4x4 acc, 128-thr blocks, 32x64 tiles (K1/K7 640 blocks, XCD-chunked swizzle).
// K5 removed: K3 emits per-block (max, sum-exp); K6 combines deterministically;
// K7 applies exp(l - gmax) in A-staging. No atomics, no memset.

#define NEGINF (-1e30f)

__device__ inline float waveRedSum(float v){
  #pragma unroll
  for (int o = 32; o > 0; o >>= 1) v += __shfl_down(v, o, 64);
  return v;
}
__device__ inline float waveRedMax(float v){
  #pragma unroll
  for (int o = 32; o > 0; o >>= 1) v = fmaxf(v, __shfl_down(v, o, 64));
  return v;
}
__device__ inline float4 f4z(){ return make_float4(0.f,0.f,0.f,0.f); }

// ---------------- K1: H = feature @ W^T + Wb   [4096 x 300], K=768 ----------------
// 128 thr, tile 32(M)x64(N), 4x4 acc. 1D grid 640, XCD-chunked decode.
__global__ __launch_bounds__(128) void k1_h(const float* __restrict__ A,
                                            const float* __restrict__ W,
                                            const float* __restrict__ Wb,
                                            float* __restrict__ H){
  __shared__ float At[2][32][36];   // [buf][k][m]
  __shared__ float Bt[2][32][68];   // [buf][k][n]
  const int fid = blockIdx.x;
  const int wl  = (fid & 7) * 80 + (fid >> 3);   // bijective: 8 chunks of 80
  const int x   = wl % 5, y = wl / 5;            // y: 0..127
  const int c0 = x * 64, m0 = y * 32;
  const int t  = threadIdx.x;
  const int tr4 = (t >> 4) * 4;      // 0..28
  const int tc4 = (t & 15) * 4;      // 0..60
  const int sr  = t >> 3;            // 0..15
  const int sc  = (t & 7) * 4;       // 0..28
  const int b0 = c0 + sr, b1 = c0 + 16 + sr, b2 = c0 + 32 + sr, b3 = c0 + 48 + sr;
  float4 ra0, ra1, rb0, rb1, rb2, rb3;
#define K1_LD(kt) { \
    ra0 = *(const float4*)&A[(size_t)(m0 + sr     ) * 768 + (kt) + sc]; \
    ra1 = *(const float4*)&A[(size_t)(m0 + 16 + sr) * 768 + (kt) + sc]; \
    rb0 = (b0 < 300) ? *(const float4*)&W[(size_t)b0 * 768 + (kt) + sc] : f4z(); \
    rb1 = (b1 < 300) ? *(const float4*)&W[(size_t)b1 * 768 + (kt) + sc] : f4z(); \
    rb2 = (b2 < 300) ? *(const float4*)&W[(size_t)b2 * 768 + (kt) + sc] : f4z(); \
    rb3 = (b3 < 300) ? *(const float4*)&W[(size_t)b3 * 768 + (kt) + sc] : f4z(); }
  K1_LD(0)
  float4 acc0 = f4z(), acc1 = f4z(), acc2 = f4z(), acc3 = f4z();
  int p = 0;
  for (int kt = 0; kt < 768; kt += 32){
    #pragma unroll
    for (int i = 0; i < 4; i++){
      At[p][sc+i][sr     ] = (&ra0.x)[i];
      At[p][sc+i][16 + sr] = (&ra1.x)[i];
      Bt[p][sc+i][sr     ] = (&rb0.x)[i];
      Bt[p][sc+i][16 + sr] = (&rb1.x)[i];
      Bt[p][sc+i][32 + sr] = (&rb2.x)[i];
      Bt[p][sc+i][48 + sr] = (&rb3.x)[i];
    }
    __syncthreads();
    if (kt + 32 < 768) K1_LD(kt + 32)
    #pragma unroll
    for (int kk = 0; kk < 32; kk++){
      const float4 a4 = *(const float4*)&At[p][kk][tr4];
      const float4 b4 = *(const float4*)&Bt[p][kk][tc4];
      acc0.x += a4.x*b4.x; acc0.y += a4.x*b4.y; acc0.z += a4.x*b4.z; acc0.w += a4.x*b4.w;
      acc1.x += a4.y*b4.x; acc1.y += a4.y*b4.y; acc1.z += a4.y*b4.z; acc1.w += a4.y*b4.w;
      acc2.x += a4.z*b4.x; acc2.y += a4.z*b4.y; acc2.z += a4.z*b4.z; acc2.w += a4.z*b4.w;
      acc3.x += a4.w*b4.x; acc3.y += a4.w*b4.y; acc3.z += a4.w*b4.z; acc3.w += a4.w*b4.w;
    }
    p ^= 1;
  }
#undef K1_LD
  const int col = c0 + tc4;
  if (col < 300){
    const float4 bi = *(const float4*)&Wb[col];
    float4 o;
    o = make_float4(acc0.x+bi.x, acc0.y+bi.y, acc0.z+bi.z, acc0.w+bi.w);
    *(float4*)&H[(size_t)(m0 + tr4 + 0) * 300 + col] = o;
    o = make_float4(acc1.x+bi.x, acc1.y+bi.y, acc1.z+bi.z, acc1.w+bi.w);
    *(float4*)&H[(size_t)(m0 + tr4 + 1) * 300 + col] = o;
    o = make_float4(acc2.x+bi.x, acc2.y+bi.y, acc2.z+bi.z, acc2.w+bi.w);
    *(float4*)&H[(size_t)(m0 + tr4 + 2) * 300 + col] = o;
    o = make_float4(acc3.x+bi.x, acc3.y+bi.y, acc3.z+bi.z, acc3.w+bi.w);
    *(float4*)&H[(size_t)(m0 + tr4 + 3) * 300 + col] = o;
  }
}

// ---------------- K2: S = H @ Bmat^T (+a1b on cols<64)  [4096 x 128], K=300 --------
// Bmat[n][k] = n<64 ? a1w[n][k] : a1w[n-64][300+k]. 128 thr, 32x64 tile, 4x4 acc.
__global__ __launch_bounds__(128) void k2_s(const float* __restrict__ Hm,
                                            const float* __restrict__ a1w,
                                            const float* __restrict__ a1b,
                                            float* __restrict__ S){
  __shared__ float At[2][32][36];
  __shared__ float Bt[2][32][68];
  const int c0 = blockIdx.x * 64;
  const int m0 = blockIdx.y * 32;
  const int t  = threadIdx.x;
  const int tr4 = (t >> 4) * 4;
  const int tc4 = (t & 15) * 4;
  const int sr  = t >> 3;
  const int sc  = (t & 7) * 4;
  const int n0 = c0 + sr, n1 = c0 + 16 + sr, n2 = c0 + 32 + sr, n3 = c0 + 48 + sr;
  const float* brow0 = (n0 < 64) ? &a1w[(size_t)n0 * 600] : &a1w[(size_t)(n0 - 64) * 600 + 300];
  const float* brow1 = (n1 < 64) ? &a1w[(size_t)n1 * 600] : &a1w[(size_t)(n1 - 64) * 600 + 300];
  const float* brow2 = (n2 < 64) ? &a1w[(size_t)n2 * 600] : &a1w[(size_t)(n2 - 64) * 600 + 300];
  const float* brow3 = (n3 < 64) ? &a1w[(size_t)n3 * 600] : &a1w[(size_t)(n3 - 64) * 600 + 300];
  float4 ra0, ra1, rb0, rb1, rb2, rb3;
#define K2_LD(kt) { const int k = (kt) + sc; \
    if (k < 300){ \
      ra0 = *(const float4*)&Hm[(size_t)(m0 + sr     ) * 300 + k]; \
      ra1 = *(const float4*)&Hm[(size_t)(m0 + 16 + sr) * 300 + k]; \
      rb0 = *(const float4*)&brow0[k]; rb1 = *(const float4*)&brow1[k]; \
      rb2 = *(const float4*)&brow2[k]; rb3 = *(const float4*)&brow3[k]; \
    } else { ra0=f4z(); ra1=f4z(); rb0=f4z(); rb1=f4z(); rb2=f4z(); rb3=f4z(); } }
  K2_LD(0)
  float4 acc0 = f4z(), acc1 = f4z(), acc2 = f4z(), acc3 = f4z();
  int p = 0;
  for (int kt = 0; kt < 320; kt += 32){
    #pragma unroll
    for (int i = 0; i < 4; i++){
      At[p][sc+i][sr     ] = (&ra0.x)[i];
      At[p][sc+i][16 + sr] = (&ra1.x)[i];
      Bt[p][sc+i][sr     ] = (&rb0.x)[i];
      Bt[p][sc+i][16 + sr] = (&rb1.x)[i];
      Bt[p][sc+i][32 + sr] = (&rb2.x)[i];
      Bt[p][sc+i][48 + sr] = (&rb3.x)[i];
    }
    __syncthreads();
    if (kt + 32 < 320) K2_LD(kt + 32)
    #pragma unroll
    for (int kk = 0; kk < 32; kk++){
      const float4 a4 = *(const float4*)&At[p][kk][tr4];
      const float4 b4 = *(const float4*)&Bt[p][kk][tc4];
      acc0.x += a4.x*b4.x; acc0.y += a4.x*b4.y; acc0.z += a4.x*b4.z; acc0.w += a4.x*b4.w;
      acc1.x += a4.y*b4.x; acc1.y += a4.y*b4.y; acc1.z += a4.y*b4.z; acc1.w += a4.y*b4.w;
      acc2.x += a4.z*b4.x; acc2.y += a4.z*b4.y; acc2.z += a4.z*b4.z; acc2.w += a4.z*b4.w;
      acc3.x += a4.w*b4.x; acc3.y += a4.w*b4.y; acc3.z += a4.w*b4.z; acc3.w += a4.w*b4.w;
    }
    p ^= 1;
  }
#undef K2_LD
  const int col = c0 + tc4;
  float4 bi = f4z();
  if (col < 64) bi = *(const float4*)&a1b[col];
  float4 o;
  o = make_float4(acc0.x+bi.x, acc0.y+bi.y, acc0.z+bi.z, acc0.w+bi.w);
  *(float4*)&S[(size_t)(m0 + tr4 + 0) * 128 + col] = o;
  o = make_float4(acc1.x+bi.x, acc1.y+bi.y, acc1.z+bi.z, acc1.w+bi.w);
  *(float4*)&S[(size_t)(m0 + tr4 + 1) * 128 + col] = o;
  o = make_float4(acc2.x+bi.x, acc2.y+bi.y, acc2.z+bi.z, acc2.w+bi.w);
  *(float4*)&S[(size_t)(m0 + tr4 + 2) * 128 + col] = o;
  o = make_float4(acc3.x+bi.x, acc3.y+bi.y, acc3.z+bi.z, acc3.w+bi.w);
  *(float4*)&S[(size_t)(m0 + tr4 + 3) * 128 + col] = o;
}

// ---------------- K3: logits + mask + per-block (max, sum-exp) ----------------------
__global__ __launch_bounds__(256) void k3_logits(const float* __restrict__ S,
                                                 const float* __restrict__ adj,
                                                 const float* __restrict__ a2w,
                                                 const float* __restrict__ a2b,
                                                 float* __restrict__ L,
                                                 float* __restrict__ bm,
                                                 float* __restrict__ bs){
  __shared__ float si_s[32][64];
  __shared__ float sj_s[64][64];
  __shared__ float w_s[64];
  __shared__ float redm[4];
  __shared__ float reds[4];
  __shared__ float smax;
  const int b  = blockIdx.z;
  const int i0 = blockIdx.y * 32;
  const int j0 = blockIdx.x * 64;
  const int t  = threadIdx.x;
  if (t < 16) *(float4*)&w_s[t*4] = *(const float4*)&a2w[t*4];
  #pragma unroll
  for (int q = 0; q < 2; q++){
    int c = t + q*256; int r = c >> 4, c4 = c & 15;
    *(float4*)&si_s[r][c4*4] = *(const float4*)&S[(size_t)(b*512 + i0 + r)*128 + c4*4];
  }
  #pragma unroll
  for (int q = 0; q < 4; q++){
    int c = t + q*256; int r = c >> 4, c4 = c & 15;
    int c4s = c4 ^ (r & 7);
    *(float4*)&sj_s[r][c4s*4] = *(const float4*)&S[(size_t)(b*512 + j0 + r)*128 + 64 + c4*4];
  }
  __syncthreads();
  const int j = t & 63, iq = t >> 6;
  const float a2bv = a2b[0];
  float4 acc[8];
  #pragma unroll
  for (int ii = 0; ii < 8; ii++) acc[ii] = f4z();
  #pragma unroll
  for (int k4 = 0; k4 < 16; k4++){
    float4 sj4 = *(float4*)&sj_s[j][(k4 ^ (j & 7))*4];
    float4 w4  = *(float4*)&w_s[k4*4];
    #pragma unroll
    for (int ii = 0; ii < 8; ii++){
      int i = ii*4 + iq;
      float4 si4 = *(float4*)&si_s[i][k4*4];
      acc[ii].x += fmaxf(si4.x + sj4.x, 0.f) * w4.x;
      acc[ii].y += fmaxf(si4.y + sj4.y, 0.f) * w4.y;
      acc[ii].z += fmaxf(si4.z + sj4.z, 0.f) * w4.z;
      acc[ii].w += fmaxf(si4.w + sj4.w, 0.f) * w4.w;
    }
  }
  float l_arr[8];
  float locmax = -3e38f;
  #pragma unroll
  for (int ii = 0; ii < 8; ii++){
    int i = ii*4 + iq;
    float e = ((acc[ii].x + acc[ii].y) + (acc[ii].z + acc[ii].w)) + a2bv;
    e = (e >= 0.f) ? e : 0.01f * e;
    size_t idx = (size_t)(b*512 + i0 + i)*512 + j0 + j;
    float l = (adj[idx] != 0.f) ? e : NEGINF;
    l_arr[ii] = l;
    L[idx] = l;
    locmax = fmaxf(locmax, l);
  }
  float m = waveRedMax(locmax);
  if ((t & 63) == 0) redm[t >> 6] = m;
  __syncthreads();
  if (t == 0) smax = fmaxf(fmaxf(redm[0], redm[1]), fmaxf(redm[2], redm[3]));
  __syncthreads();
  const float mb = smax;
  float s = 0.f;
  #pragma unroll
  for (int ii = 0; ii < 8; ii++) s += __expf(l_arr[ii] - mb);
  s = waveRedSum(s);
  if ((t & 63) == 0) reds[t >> 6] = s;
  __syncthreads();
  if (t == 0){
    const int bid = (blockIdx.z * 16 + blockIdx.y) * 8 + blockIdx.x;
    bm[bid] = mb;
    bs[bid] = (reds[0] + reds[1]) + (reds[2] + reds[3]);
  }
}

// ---------------- K6: combine per-block (m,s) -> per-batch (maxg, sums) -------------
__global__ __launch_bounds__(128) void k6_red(const float* __restrict__ bm,
                                              const float* __restrict__ bs,
                                              float* __restrict__ sums,
                                              float* __restrict__ maxg){
  const int b = blockIdx.x, t = threadIdx.x;
  const float m = bm[b*128 + t];
  float mm = waveRedMax(m);
  __shared__ float r2m[2];
  __shared__ float mgs;
  if ((t & 63) == 0) r2m[t >> 6] = mm;
  __syncthreads();
  if (t == 0) mgs = fmaxf(r2m[0], r2m[1]);
  __syncthreads();
  const float mg = mgs;
  float v = bs[b*128 + t] * __expf(m - mg);
  v = waveRedSum(v);
  __shared__ float r2s[2];
  if ((t & 63) == 0) r2s[t >> 6] = v;
  __syncthreads();
  if (t == 0){ sums[b] = r2s[0] + r2s[1]; maxg[b] = mg; }
}

// ---------------- K7: out = (exp(L-maxg) @ H) / sums; per-batch [512x300], K=512 ----
// 128 thr, 32x64 tile, 4x4 acc. 1D grid 640, XCD-chunked (one batch per XCD).
__global__ __launch_bounds__(128) void k7_out(const float* __restrict__ Lr,
                                              const float* __restrict__ Hm,
                                              const float* __restrict__ sums,
                                              const float* __restrict__ maxg,
                                              float* __restrict__ out){
  __shared__ float At[2][32][36];   // exp'd A, [k][m]
  __shared__ float Bs[2][32][68];   // H tile, [k][n] row-major
  const int fid = blockIdx.x;
  const int wl  = (fid & 7) * 80 + (fid >> 3);
  const int bz  = wl / 80;                 // batch (== fid&7)
  const int rem = wl % 80;
  const int y   = rem / 5, x = rem % 5;    // y: 0..15
  const int c0 = x * 64, m0 = y * 32;
  const int t  = threadIdx.x;
  const int tr4 = (t >> 4) * 4;
  const int tc4 = (t & 15) * 4;
  const int sr  = t >> 3;             // 0..15  (A staging)
  const int sc  = (t & 7) * 4;        // 0..28
  const int bkr = t >> 4;             // 0..7   (B staging)
  const int bc4 = (t & 15) * 4;       // 0..60
  const int colB = c0 + bc4;
  const float mx = maxg[bz];
  const size_t Lb = (size_t)bz * 262144;
  const size_t Hb = (size_t)bz * 512;
  float4 ra0, ra1, rb0, rb1, rb2, rb3;
#define K7_LD(kt) { \
    ra0 = *(const float4*)&Lr[Lb + (size_t)(m0 + sr     ) * 512 + (kt) + sc]; \
    ra1 = *(const float4*)&Lr[Lb + (size_t)(m0 + 16 + sr) * 512 + (kt) + sc]; \
    if (colB < 300){ \
      rb0 = *(const float4*)&Hm[(Hb + (kt) + bkr     ) * 300 + colB]; \
      rb1 = *(const float4*)&Hm[(Hb + (kt) + 8 + bkr ) * 300 + colB]; \
      rb2 = *(const float4*)&Hm[(Hb + (kt) + 16 + bkr) * 300 + colB]; \
      rb3 = *(const float4*)&Hm[(Hb + (kt) + 24 + bkr) * 300 + colB]; \
    } else { rb0=f4z(); rb1=f4z(); rb2=f4z(); rb3=f4z(); } }
  K7_LD(0)
  float4 acc0 = f4z(), acc1 = f4z(), acc2 = f4z(), acc3 = f4z();
  int p = 0;
  for (int kt = 0; kt < 512; kt += 32){
    #pragma unroll
    for (int i = 0; i < 4; i++){
      At[p][sc+i][sr     ] = __expf((&ra0.x)[i] - mx);
      At[p][sc+i][16 + sr] = __expf((&ra1.x)[i] - mx);
    }
    *(float4*)&Bs[p][bkr     ][bc4] = rb0;
    *(float4*)&Bs[p][8 + bkr ][bc4] = rb1;
    *(float4*)&Bs[p][16 + bkr][bc4] = rb2;
    *(float4*)&Bs[p][24 + bkr][bc4] = rb3;
    __syncthreads();
    if (kt + 32 < 512) K7_LD(kt + 32)
    #pragma unroll
    for (int kk = 0; kk < 32; kk++){
      const float4 a4 = *(const float4*)&At[p][kk][tr4];
      const float4 b4 = *(const float4*)&Bs[p][kk][tc4];
      acc0.x += a4.x*b4.x; acc0.y += a4.x*b4.y; acc0.z += a4.x*b4.z; acc0.w += a4.x*b4.w;
      acc1.x += a4.y*b4.x; acc1.y += a4.y*b4.y; acc1.z += a4.y*b4.z; acc1.w += a4.y*b4.w;
      acc2.x += a4.z*b4.x; acc2.y += a4.z*b4.y; acc2.z += a4.z*b4.z; acc2.w += a4.z*b4.w;
      acc3.x += a4.w*b4.x; acc3.y += a4.w*b4.y; acc3.z += a4.w*b4.z; acc3.w += a4.w*b4.w;
    }
    p ^= 1;
  }
#undef K7_LD
  const float invs = 1.0f / sums[bz];
  const int col = c0 + tc4;
  if (col < 300){
    float4 o;
    o = make_float4(acc0.x*invs, acc0.y*invs, acc0.z*invs, acc0.w*invs);
    *(float4*)&out[(Hb + m0 + tr4 + 0) * 300 + col] = o;
    o = make_float4(acc1.x*invs, acc1.y*invs, acc1.z*invs, acc1.w*invs);
    *(float4*)&out[(Hb + m0 + tr4 + 1) * 300 + col] = o;
    o = make_float4(acc2.x*invs, acc2.y*invs, acc2.z*invs, acc2.w*invs);
    *(float4*)&out[(Hb + m0 + tr4 + 2) * 300 + col] = o;
    o = make_float4(acc3.x*invs, acc3.y*invs, acc3.z*invs, acc3.w*invs);
    *(float4*)&out[(Hb + m0 + tr4 + 3) * 300 + col] = o;
  }
}

extern "C" void kernel_launch(void* const* d_in, const int* in_sizes, int n_in,
                              void* d_out, int out_size, void* d_ws, size_t ws_size,
                              hipStream_t stream){
  const float* adj  = (const float*)d_in[0];
  const float* feat = (const float*)d_in[1];
  const float* Ww   = (const float*)d_in[2];
  const float* Wb   = (const float*)d_in[3];
  const float* a1w  = (const float*)d_in[4];
  const float* a1b  = (const float*)d_in[5];
  const float* a2w  = (const float*)d_in[6];
  const float* a2b  = (const float*)d_in[7];
  float* out = (float*)d_out;
  char* ws = (char*)d_ws;

  float* H    = (float*)(ws + 0);           // 4,915,200 B
  float* S    = (float*)(ws + 4915200);     // 2,097,152 B
  float* L    = (float*)(ws + 7012352);     // 8,388,608 B
  float* bm   = (float*)(ws + 15400960);    // 4,096 B  (1024 block maxes)
  float* bs   = (float*)(ws + 15405056);    // 4,096 B  (1024 block sums)
  float* sums = (float*)(ws + 15409152);    // 32 B
  float* maxg = (float*)(ws + 15409216);    // 32 B

  k1_h     <<<dim3(640),      dim3(128), 0, stream>>>(feat, Ww, Wb, H);
  k2_s     <<<dim3(2, 128),   dim3(128), 0, stream>>>(H, a1w, a1b, S);
  k3_logits<<<dim3(8, 16, 8), dim3(256), 0, stream>>>(S, adj, a2w, a2b, L, bm, bs);
  k6_red   <<<dim3(8),        dim3(128), 0, stream>>>(bm, bs, sums, maxg);
  k7_out   <<<dim3(640),      dim3(128), 0, stream>>>(L, H, sums, maxg, out);
}